// Round 8
// baseline (107.768 us; speedup 1.0000x reference)
//
#include <hip/hip_runtime.h>
#include <hip/hip_bf16.h>
#include <stdint.h>

// Chamfer loss: dist = ||x||^2 + ||y||^2 - 2 x.y via pure bf16 MFMA, K=128.
// R8: barrier-free GEMM. A-panel (256xK128, 64 KB) staged once into LDS
// (proven gload_lds geometry + XOR swizzle) -> ONE __syncthreads. B is NOT
// LDS-staged: fragments load directly from L2 into registers (coalesced:
// 16 lanes x 64 contiguous B per row), depth-1 prefetch with compile-time
// parity buffers. Epilogue commits per-wave directly to atomicMin (no LDS
// combine, no barriers): miny 2 waves/col, minx 4 waves/row redundancy.
// After the single sync, the 8 waves run fully unsynchronized - no vmcnt(0)
// convoy, wave TLP + ILP hides B latency (common-mistake #7: B is L2-fit).

typedef __bf16  bf16x8 __attribute__((ext_vector_type(8)));
typedef float   f32x4  __attribute__((ext_vector_type(4)));

#define NPTS 8192
#define DIM  128
#define KC   128   // bf16 K (pure hi)

__device__ __forceinline__ void gload_lds16(const void* gsrc, void* ldst) {
  __builtin_amdgcn_global_load_lds(
      (const __attribute__((address_space(1))) uint32_t*)(uintptr_t)gsrc,
      (__attribute__((address_space(3))) uint32_t*)(uintptr_t)ldst,
      16, 0, 0);
}

// ---------------------------------------------------------------- prep ----
// One float4 per thread (32 threads/row). Row norms (fp32 of ORIGINAL data),
// bf16 cast of (-2x) for X / (y) for Y, min arrays -> +inf.
__global__ __launch_bounds__(256) void prep_kernel(
    const float* __restrict__ x, const float* __restrict__ y,
    unsigned short* __restrict__ Xc, unsigned short* __restrict__ Yc,
    float* __restrict__ x2, float* __restrict__ y2,
    unsigned int* __restrict__ minx, unsigned int* __restrict__ miny)
{
  const int gt  = blockIdx.x * 256 + threadIdx.x;   // 0 .. 524287
  const int row = gt >> 5;                          // 0 .. 16383
  const int seg = gt & 31;                          // float4 slot in row
  const bool isx = row < NPTS;
  const float* src        = isx ? (x  + (size_t)row * DIM) : (y  + (size_t)(row - NPTS) * DIM);
  unsigned short* dst     = isx ? (Xc + (size_t)row * KC)  : (Yc + (size_t)(row - NPTS) * KC);

  f32x4 v = *reinterpret_cast<const f32x4*>(src + seg * 4);
  float sq = v[0]*v[0] + v[1]*v[1] + v[2]*v[2] + v[3]*v[3];
  #pragma unroll
  for (int m = 1; m <= 16; m <<= 1) sq += __shfl_xor(sq, m);   // 32-lane segmented reduce
  if (seg == 0) { if (isx) x2[row] = sq; else y2[row - NPTS] = sq; }

  const float scale = isx ? -2.0f : 1.0f;           // fold the -2 into X (exact)
  unsigned short hb[4];
  #pragma unroll
  for (int i = 0; i < 4; ++i) {
    __hip_bfloat16 h = __float2bfloat16(scale * v[i]);
    hb[i] = __builtin_bit_cast(unsigned short, h);
  }
  *reinterpret_cast<ushort4*>(dst + seg * 4) = make_ushort4(hb[0], hb[1], hb[2], hb[3]);

  if (gt < NPTS)          minx[gt]        = 0x7F800000u;   // +inf
  else if (gt < 2 * NPTS) miny[gt - NPTS] = 0x7F800000u;
}

// ---------------------------------------------------------------- gemm ----
// 512 threads / 8 waves (2x4); per wave 128x64 via acc[8][4] of
// mfma_f32_16x16x32_bf16. Block owns (bi, bj0..bj0+3): 4 tiles, 8 phases.
__global__ __launch_bounds__(512, 2) void chamfer_gemm(
    const unsigned short* __restrict__ Xc, const unsigned short* __restrict__ Yc,
    const float* __restrict__ x2, const float* __restrict__ y2,
    unsigned int* __restrict__ minx, unsigned int* __restrict__ miny)
{
  __shared__ alignas(16) unsigned short As[2][256 * 64];   // 64 KB, A resident

  const int tid  = threadIdx.x;
  const int lane = tid & 63;
  const int w    = tid >> 6;        // 0..7
  const int wr   = w >> 2;          // 0..1  (rows: wr*128)
  const int wc   = w & 3;           // 0..3  (cols: wc*64)

  // XCD map: xcd = b&7 -> bi in [xcd*4, xcd*4+4); local = b>>3 (0..31):
  const int b     = blockIdx.x;
  const int local = b >> 3;
  const int bi    = (b & 7) * 4 + (local >> 3);
  const int bj0   = (local & 7) * 4;

  // A staging (proven): LDS byte = row*128 + slot*16 (linear), slot = tid&7,
  // row = l*64 + (tid>>3); source pre-swizzled: kgroup = slot ^ (row&7).
  const int r64  = tid >> 3;               // 0..63
  const int kgrp = (tid & 7) ^ (r64 & 7);
  const unsigned short* Abase = Xc + (size_t)(bi * 256 + r64) * KC + kgrp * 8;
  const int wofs = w * 1024;               // wave-uniform LDS base offset

  #pragma unroll
  for (int kt = 0; kt < 2; ++kt) {
    const unsigned short* Asrc = Abase + kt * 64;
    char* Ad = (char*)&As[kt][0] + wofs;
    #pragma unroll
    for (int l = 0; l < 4; ++l)
      gload_lds16(Asrc + (size_t)l * 64 * KC, Ad + l * 8192);
  }

  __syncthreads();   // the ONLY block-wide sync: A panel resident

  // B fragment base addresses (direct from global/L2, no LDS):
  // lane reads Yc[col][koct*8 .. +8), col = wc*64+ni*16+(lane&15),
  // koct = kt*8 + ks*4 + (lane>>4)  ->  16 lanes x 64 contiguous B per row.
  const unsigned short* Bf[4];
  #pragma unroll
  for (int ni = 0; ni < 4; ++ni)
    Bf[ni] = Yc + (size_t)(wc * 64 + ni * 16 + (lane & 15)) * KC + (lane >> 4) * 8;

  int4 bq[2][4][2];   // [phase parity][ni][ks] - indices compile-time (unrolled)
  #pragma unroll
  for (int ni = 0; ni < 4; ++ni)
    #pragma unroll
    for (int ks = 0; ks < 2; ++ks)
      bq[0][ni][ks] = *reinterpret_cast<const int4*>(Bf[ni] + (size_t)bj0 * 256 * KC + ks * 32);

  float rowrun0 = 3.0e38f, rowrun1 = 3.0e38f;   // running minx per lane

  #pragma unroll
  for (int t = 0; t < 4; ++t) {
    const int bj = bj0 + t;

    // acc init = x2[row] + y2[col]  ->  accumulator IS the distance
    f32x4 acc[8][4];
    {
      f32x4 xv; float yv[4];
      #pragma unroll
      for (int ni = 0; ni < 4; ++ni)
        yv[ni] = y2[bj * 256 + wc * 64 + ni * 16 + (lane & 15)];
      #pragma unroll
      for (int mi = 0; mi < 8; ++mi) {
        xv = *reinterpret_cast<const f32x4*>(x2 + bi * 256 + wr * 128 + mi * 16 + ((lane >> 4) << 2));
        #pragma unroll
        for (int ni = 0; ni < 4; ++ni)
          #pragma unroll
          for (int r = 0; r < 4; ++r)
            acc[mi][ni][r] = xv[r] + yv[ni];
      }
    }

    #pragma unroll
    for (int kt = 0; kt < 2; ++kt) {
      const int p = (t * 2 + kt) & 1;

      // depth-1 prefetch: issue next phase's 8 fragment loads before MFMA
      if (t * 2 + kt < 7) {
        const int nt  = (kt == 1) ? t + 1 : t;
        const int nkt = kt ^ 1;
        #pragma unroll
        for (int ni = 0; ni < 4; ++ni)
          #pragma unroll
          for (int ks = 0; ks < 2; ++ks)
            bq[p ^ 1][ni][ks] = *reinterpret_cast<const int4*>(
                Bf[ni] + (size_t)(bj0 + nt) * 256 * KC + nkt * 64 + ks * 32);
      }

      const char* Ab = (const char*)&As[kt][0];
      #pragma unroll
      for (int mi = 0; mi < 8; ++mi) {
        const int rowl = wr * 128 + mi * 16 + (lane & 15);
        const int swz  = (rowl & 7) << 4;
        const bf16x8 a0 = *reinterpret_cast<const bf16x8*>(Ab + rowl * 128 + ((  0 + ((lane >> 4) << 4)) ^ swz));
        const bf16x8 a1 = *reinterpret_cast<const bf16x8*>(Ab + rowl * 128 + (( 64 + ((lane >> 4) << 4)) ^ swz));
        #pragma unroll
        for (int ni = 0; ni < 4; ++ni) {
          acc[mi][ni] = __builtin_amdgcn_mfma_f32_16x16x32_bf16(
              a0, __builtin_bit_cast(bf16x8, bq[p][ni][0]), acc[mi][ni], 0, 0, 0);
          acc[mi][ni] = __builtin_amdgcn_mfma_f32_16x16x32_bf16(
              a1, __builtin_bit_cast(bf16x8, bq[p][ni][1]), acc[mi][ni], 0, 0, 0);
        }
      }
    }

    // ---- epilogue (tile t): per-wave min folds -> direct atomics ----
    // column mins over this wave's 128 rows (per ni, fold over lane>>4)
    float cm[4];
    #pragma unroll
    for (int ni = 0; ni < 4; ++ni) {
      float m = 3.0e38f;
      #pragma unroll
      for (int mi = 0; mi < 8; ++mi)
        #pragma unroll
        for (int r = 0; r < 4; ++r)
          m = fminf(m, acc[mi][ni][r]);
      cm[ni] = m;
    }
    {
      const bool hb0 = (lane & 16) != 0;
      float s0 = hb0 ? cm[0] : cm[2];
      float s1 = hb0 ? cm[1] : cm[3];
      float r0 = __shfl_xor(s0, 16);
      float r1 = __shfl_xor(s1, 16);
      float t0 = fminf(hb0 ? cm[2] : cm[0], r0);
      float t1 = fminf(hb0 ? cm[3] : cm[1], r1);
      const bool hb1 = (lane & 32) != 0;
      float s  = hb1 ? t0 : t1;
      float rr = __shfl_xor(s, 32);
      float cfin = fminf(hb1 ? t1 : t0, rr);
      const int ni = (hb0 ? 2 : 0) + (hb1 ? 1 : 0);    // bitrev2(lane>>4)
      // 2 waves (wr=0,1) combine via the atomic itself
      atomicMin(&miny[bj * 256 + wc * 64 + ni * 16 + (lane & 15)],
                __float_as_uint(fmaxf(cfin, 0.f)));
    }

    // row mins: reduce over ni in regs (32 values), 4-step fold over lane&15
    float rm[32];
    #pragma unroll
    for (int mi = 0; mi < 8; ++mi)
      #pragma unroll
      for (int r = 0; r < 4; ++r)
        rm[mi * 4 + r] = fminf(fminf(acc[mi][0][r], acc[mi][1][r]),
                               fminf(acc[mi][2][r], acc[mi][3][r]));
    #pragma unroll
    for (int b2 = 0; b2 < 4; ++b2) {
      const int  half = 16 >> b2;
      const bool up   = (lane >> b2) & 1;
      #pragma unroll
      for (int i = 0; i < half; ++i) {
        float snd = up ? rm[i] : rm[i + half];
        float rcv = __shfl_xor(snd, 1 << b2);
        rm[i] = fminf(up ? rm[i + half] : rm[i], rcv);
      }
    }
    rowrun0 = fminf(rowrun0, rm[0]);
    rowrun1 = fminf(rowrun1, rm[1]);
  }

  // minx: one atomic per surviving element (4 wc-waves combine via atomic)
  {
    const int base = ((lane & 1) << 4) | ((lane & 2) << 2) | (lane & 4) | ((lane & 8) >> 2);
    const int idx0 = base;         // e = 0
    const int idx1 = base | 1;     // e = 1
    const int row0 = wr * 128 + (idx0 >> 2) * 16 + ((lane >> 4) << 2) + (idx0 & 3);
    const int row1 = wr * 128 + (idx1 >> 2) * 16 + ((lane >> 4) << 2) + (idx1 & 3);
    atomicMin(&minx[bi * 256 + row0], __float_as_uint(fmaxf(rowrun0, 0.f)));
    atomicMin(&minx[bi * 256 + row1], __float_as_uint(fmaxf(rowrun1, 0.f)));
  }
}

// ------------------------------------------------------------- finalize ----
__global__ __launch_bounds__(256) void finalize_kernel(
    const unsigned int* __restrict__ minx, const unsigned int* __restrict__ miny,
    float* __restrict__ out)
{
  // all stored patterns are non-negative floats; reinterpret directly
  const f32x4* mx = (const f32x4*)minx;
  const f32x4* my = (const f32x4*)miny;
  float s = 0.f;
  for (int i = threadIdx.x; i < NPTS / 4; i += 256) {
    f32x4 a = mx[i], b = my[i];
    s += (a[0] + a[1] + a[2] + a[3]) + (b[0] + b[1] + b[2] + b[3]);
  }
  #pragma unroll
  for (int m = 32; m >= 1; m >>= 1) s += __shfl_xor(s, m);
  __shared__ float partial[4];
  if ((threadIdx.x & 63) == 0) partial[threadIdx.x >> 6] = s;
  __syncthreads();
  if (threadIdx.x == 0)
    out[0] = (partial[0] + partial[1] + partial[2] + partial[3]) * (1.0f / (float)NPTS);
}

// ---------------------------------------------------------------- launch ----
extern "C" void kernel_launch(void* const* d_in, const int* in_sizes, int n_in,
                              void* d_out, int out_size, void* d_ws, size_t ws_size,
                              hipStream_t stream) {
  (void)in_sizes; (void)n_in; (void)out_size; (void)ws_size;
  const float* x = (const float*)d_in[0];
  const float* y = (const float*)d_in[1];
  char* ws = (char*)d_ws;

  // ws layout: Xc 2MB | Yc 2MB | x2 32KB | y2 32KB | minx 32KB | miny 32KB
  unsigned short* Xc  = (unsigned short*)(ws);
  unsigned short* Yc  = (unsigned short*)(ws + 2097152);
  float*          x2  = (float*)(ws + 4194304);
  float*          y2  = (float*)(ws + 4227072);
  unsigned int*   mnx = (unsigned int*)(ws + 4259840);
  unsigned int*   mny = (unsigned int*)(ws + 4292608);
  float*          out = (float*)d_out;

  prep_kernel<<<2048, 256, 0, stream>>>(x, y, Xc, Yc, x2, y2, mnx, mny);
  chamfer_gemm<<<256, 512, 0, stream>>>(Xc, Yc, x2, y2, mnx, mny);
  finalize_kernel<<<1, 256, 0, stream>>>(mnx, mny, out);
}